// Round 1
// baseline (537.340 us; speedup 1.0000x reference)
//
#include <hip/hip_runtime.h>
#include <stdint.h>

#define NUM_TOKENS 16384
#define DIM        4096
#define NEXP       256
#define MB         64      // tokens per block
#define BK         64      // K per staging step
#define NWAVES     8
#define MARGIN     2e-3f   // flag tokens whose top1-top2 gap is below this
#define CAP        16384   // refinement list capacity

typedef __attribute__((ext_vector_type(4))) float   f32x4;
typedef __attribute__((ext_vector_type(8))) __bf16  bf16x8;
typedef __attribute__((ext_vector_type(8))) unsigned short u16x8;

static __device__ __forceinline__ unsigned short f32_to_bf16(float f) {
    unsigned int u = __float_as_uint(f);
    u += 0x7fffu + ((u >> 16) & 1u);     // round-to-nearest-even
    return (unsigned short)(u >> 16);
}
static __device__ __forceinline__ float bf16_to_f32(unsigned short h) {
    return __uint_as_float(((unsigned int)h) << 16);
}

// ---------------------------------------------------------------- kernel 1
// Split weight fp32 -> (hi, lo) bf16 pair; zero the refinement counter.
__global__ void split_weights(const float* __restrict__ w,
                              unsigned short* __restrict__ whi,
                              unsigned short* __restrict__ wlo,
                              int* __restrict__ counter) {
    if (blockIdx.x == 0 && threadIdx.x == 0) *counter = 0;
    const int n4 = NEXP * DIM / 4;
    const int stride = gridDim.x * blockDim.x;
    for (int i = blockIdx.x * blockDim.x + threadIdx.x; i < n4; i += stride) {
        float4 v = ((const float4*)w)[i];
        ushort4 h, l;
        h.x = f32_to_bf16(v.x); l.x = f32_to_bf16(v.x - bf16_to_f32(h.x));
        h.y = f32_to_bf16(v.y); l.y = f32_to_bf16(v.y - bf16_to_f32(h.y));
        h.z = f32_to_bf16(v.z); l.z = f32_to_bf16(v.z - bf16_to_f32(h.z));
        h.w = f32_to_bf16(v.w); l.w = f32_to_bf16(v.w - bf16_to_f32(h.w));
        ((ushort4*)whi)[i] = h;
        ((ushort4*)wlo)[i] = l;
    }
}

// ---------------------------------------------------------------- kernel 2
// Fused 3-term split-bf16 GEMM (64 tokens x 256 experts per block) + top-2.
__global__ __launch_bounds__(512, 2) void gate_main(
    const float* __restrict__ x,
    const unsigned short* __restrict__ whi,
    const unsigned short* __restrict__ wlo,
    float* __restrict__ out,           // [0,T) weights, [T,2T) indices (as float)
    int* __restrict__ counter,
    int4* __restrict__ entries)
{
    __shared__ unsigned short lAh[MB][BK];      // 8 KB
    __shared__ unsigned short lAl[MB][BK];      // 8 KB
    __shared__ unsigned short lBh[NEXP * BK];   // 32 KB
    __shared__ unsigned short lBl[NEXP * BK];   // 32 KB
    __shared__ float4 cand[NWAVES][MB];         // 8 KB

    const int tid  = threadIdx.x;
    const int wv   = tid >> 6;          // wave 0..7 -> experts [wv*32, wv*32+32)
    const int lane = tid & 63;
    const int tok0 = blockIdx.x * MB;

    // A staging: thread covers token ta, k-segment kseg..kseg+8
    const int ta   = tid >> 3;          // 0..63
    const int kseg = (tid & 7) * 8;     // 0..56
    const float* xrow = x + (size_t)(tok0 + ta) * DIM + kseg;

    // B staging coords
    const int be_sub  = lane >> 3;      // 0..7
    const int bk_off  = (lane & 7) * 8; // element offset within expert row

    const int quad = lane >> 4;
    const int col  = lane & 15;

    f32x4 acc[4][2];
    #pragma unroll
    for (int mt = 0; mt < 4; ++mt) {
        acc[mt][0] = f32x4{0.f, 0.f, 0.f, 0.f};
        acc[mt][1] = f32x4{0.f, 0.f, 0.f, 0.f};
    }

    for (int k0 = 0; k0 < DIM; k0 += BK) {
        // ---- stage A: 8 fp32/thread -> split into bf16 hi/lo in LDS
        float4 v0 = *(const float4*)(xrow + k0);
        float4 v1 = *(const float4*)(xrow + k0 + 4);
        u16x8 vh, vl;
        #define SPLIT1(val, idx) { unsigned short _h = f32_to_bf16(val); \
            vh[idx] = _h; vl[idx] = f32_to_bf16((val) - bf16_to_f32(_h)); }
        SPLIT1(v0.x, 0) SPLIT1(v0.y, 1) SPLIT1(v0.z, 2) SPLIT1(v0.w, 3)
        SPLIT1(v1.x, 4) SPLIT1(v1.y, 5) SPLIT1(v1.z, 6) SPLIT1(v1.w, 7)
        #undef SPLIT1
        *(u16x8*)&lAh[ta][kseg] = vh;
        *(u16x8*)&lAl[ta][kseg] = vl;

        // ---- stage B: all 256 experts x BK, hi+lo, via async global->LDS
        #pragma unroll
        for (int jj = 0; jj < 4; ++jj) {
            const int e = jj * 64 + wv * 8 + be_sub;
            const unsigned short* gh = whi + (size_t)e * DIM + k0 + bk_off;
            const unsigned short* gl = wlo + (size_t)e * DIM + k0 + bk_off;
            unsigned short* dh = &lBh[jj * 4096 + wv * 512]; // wave-uniform base
            unsigned short* dl = &lBl[jj * 4096 + wv * 512];
#if __has_builtin(__builtin_amdgcn_global_load_lds)
            __builtin_amdgcn_global_load_lds(
                (const __attribute__((address_space(1))) unsigned int*)gh,
                (__attribute__((address_space(3))) unsigned int*)dh, 16, 0, 0);
            __builtin_amdgcn_global_load_lds(
                (const __attribute__((address_space(1))) unsigned int*)gl,
                (__attribute__((address_space(3))) unsigned int*)dl, 16, 0, 0);
#else
            *(u16x8*)((unsigned short*)dh + (size_t)lane * 8) = *(const u16x8*)gh;
            *(u16x8*)((unsigned short*)dl + (size_t)lane * 8) = *(const u16x8*)gl;
#endif
        }
        __syncthreads();

        // ---- compute: 2 k-subtiles of 32, 24 MFMAs each
        #pragma unroll
        for (int kk = 0; kk < BK; kk += 32) {
            bf16x8 ah[4], al[4], bh[2], bl[2];
            #pragma unroll
            for (int mt = 0; mt < 4; ++mt) {
                ah[mt] = *(const bf16x8*)&lAh[mt * 16 + col][kk + quad * 8];
                al[mt] = *(const bf16x8*)&lAl[mt * 16 + col][kk + quad * 8];
            }
            #pragma unroll
            for (int nt = 0; nt < 2; ++nt) {
                const int e = wv * 32 + nt * 16 + col;
                bh[nt] = *(const bf16x8*)&lBh[e * BK + kk + quad * 8];
                bl[nt] = *(const bf16x8*)&lBl[e * BK + kk + quad * 8];
            }
            #pragma unroll
            for (int mt = 0; mt < 4; ++mt) {
                #pragma unroll
                for (int nt = 0; nt < 2; ++nt) {
                    acc[mt][nt] = __builtin_amdgcn_mfma_f32_16x16x32_bf16(ah[mt], bh[nt], acc[mt][nt], 0, 0, 0);
                    acc[mt][nt] = __builtin_amdgcn_mfma_f32_16x16x32_bf16(ah[mt], bl[nt], acc[mt][nt], 0, 0, 0);
                    acc[mt][nt] = __builtin_amdgcn_mfma_f32_16x16x32_bf16(al[mt], bh[nt], acc[mt][nt], 0, 0, 0);
                }
            }
        }
        __syncthreads();
    }

    // ---- epilogue: per-wave top-2 over its 32 experts, per token.
    // C/D layout (16x16): col = lane&15 (expert), row = quad*4 + reg (token).
    #pragma unroll
    for (int mt = 0; mt < 4; ++mt) {
        #pragma unroll
        for (int r = 0; r < 4; ++r) {
            float s0 = acc[mt][0][r]; int e0 = wv * 32 + col;
            float s1 = acc[mt][1][r]; int e1 = e0 + 16;
            float t1s, t2s; int t1e, t2e;
            if (s1 > s0) { t1s = s1; t1e = e1; t2s = s0; t2e = e0; }
            else         { t1s = s0; t1e = e0; t2s = s1; t2e = e1; }
            #pragma unroll
            for (int m = 1; m <= 8; m <<= 1) {
                float o1s = __shfl_xor(t1s, m); int o1e = __shfl_xor(t1e, m);
                float o2s = __shfl_xor(t2s, m); int o2e = __shfl_xor(t2e, m);
                bool o1_top = (o1s > t1s) || (o1s == t1s && o1e < t1e);
                if (o1_top) {
                    bool keep_t1 = (t1s > o2s) || (t1s == o2s && t1e < o2e);
                    t2s = keep_t1 ? t1s : o2s; t2e = keep_t1 ? t1e : o2e;
                    t1s = o1s; t1e = o1e;
                } else {
                    bool o1_2nd = (o1s > t2s) || (o1s == t2s && o1e < t2e);
                    if (o1_2nd) { t2s = o1s; t2e = o1e; }
                }
            }
            if (col == 0) {
                int tok = mt * 16 + quad * 4 + r;
                cand[wv][tok] = make_float4(t1s, __int_as_float(t1e), t2s, __int_as_float(t2e));
            }
        }
    }
    __syncthreads();

    // ---- final merge across waves; write outputs + near-tie flags
    if (tid < MB) {
        float4 c0 = cand[0][tid];
        float t1s = c0.x; int t1e = __float_as_int(c0.y);
        float t2s = c0.z; int t2e = __float_as_int(c0.w);
        #pragma unroll
        for (int wvi = 1; wvi < NWAVES; ++wvi) {
            float4 c = cand[wvi][tid];
            float o1s = c.x; int o1e = __float_as_int(c.y);
            float o2s = c.z; int o2e = __float_as_int(c.w);
            bool o1_top = (o1s > t1s) || (o1s == t1s && o1e < t1e);
            if (o1_top) {
                bool keep_t1 = (t1s > o2s) || (t1s == o2s && t1e < o2e);
                t2s = keep_t1 ? t1s : o2s; t2e = keep_t1 ? t1e : o2e;
                t1s = o1s; t1e = o1e;
            } else {
                bool o1_2nd = (o1s > t2s) || (o1s == t2s && o1e < t2e);
                if (o1_2nd) { t2s = o1s; t2e = o1e; }
            }
        }
        const int gtok = tok0 + tid;
        out[gtok] = 1.0f;                       // STE forward value at argmax
        out[NUM_TOKENS + gtok] = (float)t1e;    // index as float
        if (t1s - t2s < MARGIN) {
            int slot = atomicAdd(counter, 1);
            if (slot < CAP) entries[slot] = make_int4(gtok, t1e, t2e, 0);
        }
    }
}

// ---------------------------------------------------------------- kernel 3
// fp64 re-verification of near-tie tokens (one wave per flagged token).
__global__ void refine(const float* __restrict__ x,
                       const float* __restrict__ w,
                       const int* __restrict__ counter,
                       const int4* __restrict__ entries,
                       float* __restrict__ out) {
    const int gwave  = (blockIdx.x * blockDim.x + threadIdx.x) >> 6;
    const int lane   = threadIdx.x & 63;
    const int nwaves = (gridDim.x * blockDim.x) >> 6;
    int n = *counter; if (n > CAP) n = CAP;
    for (int i = gwave; i < n; i += nwaves) {
        int4 e = entries[i];
        const float* xr = x + (size_t)e.x * DIM;
        const float* w1 = w + (size_t)e.y * DIM;
        const float* w2 = w + (size_t)e.z * DIM;
        double d1 = 0.0, d2 = 0.0;
        for (int k = lane; k < DIM; k += 64) {
            double xv = (double)xr[k];
            d1 += xv * (double)w1[k];
            d2 += xv * (double)w2[k];
        }
        #pragma unroll
        for (int m = 32; m > 0; m >>= 1) {
            d1 += __shfl_xor(d1, m);
            d2 += __shfl_xor(d2, m);
        }
        if (lane == 0) {
            int best = (d1 > d2) ? e.y : ((d2 > d1) ? e.z : (e.y < e.z ? e.y : e.z));
            out[NUM_TOKENS + e.x] = (float)best;
        }
    }
}

// ---------------------------------------------------------------- launcher
extern "C" void kernel_launch(void* const* d_in, const int* in_sizes, int n_in,
                              void* d_out, int out_size, void* d_ws, size_t ws_size,
                              hipStream_t stream) {
    const float* x = (const float*)d_in[0];
    const float* w = (const float*)d_in[1];
    float* out = (float*)d_out;

    char* ws = (char*)d_ws;
    unsigned short* whi = (unsigned short*)ws;                                // 2 MB
    unsigned short* wlo = (unsigned short*)(ws + (size_t)NEXP * DIM * 2);     // 2 MB
    int*  counter = (int*)(ws + (size_t)NEXP * DIM * 4);
    int4* entries = (int4*)(ws + (size_t)NEXP * DIM * 4 + 16);                // 256 KB

    split_weights<<<256, 256, 0, stream>>>(w, whi, wlo, counter);
    gate_main<<<NUM_TOKENS / MB, 512, 0, stream>>>(x, whi, wlo, out, counter, entries);
    refine<<<32, 256, 0, stream>>>(x, w, counter, entries, out);
}

// Round 2
// 497.831 us; speedup vs baseline: 1.0794x; 1.0794x over previous
//
#include <hip/hip_runtime.h>
#include <stdint.h>

#define NUM_TOKENS 16384
#define DIM        4096
#define NEXP       256
#define MB         64      // tokens per block
#define BK         64      // K per staging step
#define APAD       72      // A row stride in elements (+8 kills bank conflicts, keeps 16B align)
#define NWAVES     8
#define MARGIN     2e-3f   // flag tokens whose top1-top2 gap is below this
#define CAP        16384   // refinement list capacity

typedef __attribute__((ext_vector_type(4))) float   f32x4;
typedef __attribute__((ext_vector_type(8))) __bf16  bf16x8;
typedef __attribute__((ext_vector_type(8))) unsigned short u16x8;

static __device__ __forceinline__ unsigned short f32_to_bf16(float f) {
    unsigned int u = __float_as_uint(f);
    u += 0x7fffu + ((u >> 16) & 1u);     // round-to-nearest-even
    return (unsigned short)(u >> 16);
}
static __device__ __forceinline__ float bf16_to_f32(unsigned short h) {
    return __uint_as_float(((unsigned int)h) << 16);
}

// ---------------------------------------------------------------- kernel 1
// Split weight fp32 -> (hi, lo) bf16 pair; zero the refinement counter.
__global__ void split_weights(const float* __restrict__ w,
                              unsigned short* __restrict__ whi,
                              unsigned short* __restrict__ wlo,
                              int* __restrict__ counter) {
    if (blockIdx.x == 0 && threadIdx.x == 0) *counter = 0;
    const int n4 = NEXP * DIM / 4;
    const int stride = gridDim.x * blockDim.x;
    for (int i = blockIdx.x * blockDim.x + threadIdx.x; i < n4; i += stride) {
        float4 v = ((const float4*)w)[i];
        ushort4 h, l;
        h.x = f32_to_bf16(v.x); l.x = f32_to_bf16(v.x - bf16_to_f32(h.x));
        h.y = f32_to_bf16(v.y); l.y = f32_to_bf16(v.y - bf16_to_f32(h.y));
        h.z = f32_to_bf16(v.z); l.z = f32_to_bf16(v.z - bf16_to_f32(h.z));
        h.w = f32_to_bf16(v.w); l.w = f32_to_bf16(v.w - bf16_to_f32(h.w));
        ((ushort4*)whi)[i] = h;
        ((ushort4*)wlo)[i] = l;
    }
}

// ---------------------------------------------------------------- kernel 2
// Fused 3-term split-bf16 GEMM (64 tokens x 256 experts per block) + top-2.
// B is stored in LDS with an XOR chunk swizzle (chunk' = chunk ^ (e&7)),
// realized on the WRITE side by permuting the per-lane global source address
// (global_load_lds dest is forced to base+lane*16). A rows are padded to 72.
__global__ __launch_bounds__(512, 2) void gate_main(
    const float* __restrict__ x,
    const unsigned short* __restrict__ whi,
    const unsigned short* __restrict__ wlo,
    float* __restrict__ out,           // [0,T) weights, [T,2T) indices (as float)
    int* __restrict__ counter,
    int4* __restrict__ entries)
{
    __shared__ unsigned short lAh[MB][APAD];    // 9 KB
    __shared__ unsigned short lAl[MB][APAD];    // 9 KB
    __shared__ unsigned short lBh[NEXP * BK];   // 32 KB
    __shared__ unsigned short lBl[NEXP * BK];   // 32 KB
    __shared__ float4 cand[NWAVES][MB];         // 8 KB

    const int tid  = threadIdx.x;
    const int wv   = tid >> 6;          // wave 0..7 -> experts [wv*32, wv*32+32)
    const int lane = tid & 63;
    const int tok0 = blockIdx.x * MB;

    // A staging: thread covers token ta, k-segment kseg..kseg+8
    const int ta   = tid >> 3;          // 0..63
    const int kseg = (tid & 7) * 8;     // 0..56
    const float* xrow = x + (size_t)(tok0 + ta) * DIM + kseg;

    // B staging coords (XOR-swizzled source chunk).
    // lane l writes LDS chunk (l&7) of expert (base + (l>>3)); that slot must
    // hold global chunk ((l&7) ^ (e&7)), and e&7 == (l>>3).
    const int esub   = lane >> 3;                 // 0..7, == e&7
    const int bk_off = ((lane & 7) ^ esub) * 8;   // swizzled source element offset

    const int quad = lane >> 4;
    const int col  = lane & 15;

    f32x4 acc[4][2];
    #pragma unroll
    for (int mt = 0; mt < 4; ++mt) {
        acc[mt][0] = f32x4{0.f, 0.f, 0.f, 0.f};
        acc[mt][1] = f32x4{0.f, 0.f, 0.f, 0.f};
    }

    for (int k0 = 0; k0 < DIM; k0 += BK) {
        // ---- stage B first: async global->LDS DMA overlaps the A split VALU work
        #pragma unroll
        for (int jj = 0; jj < 4; ++jj) {
            const int e = jj * 64 + wv * 8 + esub;
            const unsigned short* gh = whi + (size_t)e * DIM + k0 + bk_off;
            const unsigned short* gl = wlo + (size_t)e * DIM + k0 + bk_off;
            unsigned short* dh = &lBh[jj * 4096 + wv * 512]; // wave-uniform base
            unsigned short* dl = &lBl[jj * 4096 + wv * 512];
            __builtin_amdgcn_global_load_lds(
                (const __attribute__((address_space(1))) unsigned int*)gh,
                (__attribute__((address_space(3))) unsigned int*)dh, 16, 0, 0);
            __builtin_amdgcn_global_load_lds(
                (const __attribute__((address_space(1))) unsigned int*)gl,
                (__attribute__((address_space(3))) unsigned int*)dl, 16, 0, 0);
        }

        // ---- stage A: 8 fp32/thread -> split into bf16 hi/lo in LDS
        float4 v0 = *(const float4*)(xrow + k0);
        float4 v1 = *(const float4*)(xrow + k0 + 4);
        u16x8 vh, vl;
        #define SPLIT1(val, idx) { unsigned short _h = f32_to_bf16(val); \
            vh[idx] = _h; vl[idx] = f32_to_bf16((val) - bf16_to_f32(_h)); }
        SPLIT1(v0.x, 0) SPLIT1(v0.y, 1) SPLIT1(v0.z, 2) SPLIT1(v0.w, 3)
        SPLIT1(v1.x, 4) SPLIT1(v1.y, 5) SPLIT1(v1.z, 6) SPLIT1(v1.w, 7)
        #undef SPLIT1
        *(u16x8*)&lAh[ta][kseg] = vh;
        *(u16x8*)&lAl[ta][kseg] = vl;

        __syncthreads();

        // ---- compute: 2 k-subtiles of 32, 24 MFMAs each
        #pragma unroll
        for (int kk = 0; kk < BK; kk += 32) {
            const int kc = kk >> 3;               // chunk base: 0 or 4
            bf16x8 ah[4], al[4], bh[2], bl[2];
            #pragma unroll
            for (int mt = 0; mt < 4; ++mt) {
                ah[mt] = *(const bf16x8*)&lAh[mt * 16 + col][kk + quad * 8];
                al[mt] = *(const bf16x8*)&lAl[mt * 16 + col][kk + quad * 8];
            }
            #pragma unroll
            for (int nt = 0; nt < 2; ++nt) {
                const int e = wv * 32 + nt * 16 + col;
                const int cpos = (((kc + quad) ^ (e & 7)) * 8); // unswizzle
                bh[nt] = *(const bf16x8*)&lBh[e * BK + cpos];
                bl[nt] = *(const bf16x8*)&lBl[e * BK + cpos];
            }
            #pragma unroll
            for (int mt = 0; mt < 4; ++mt) {
                #pragma unroll
                for (int nt = 0; nt < 2; ++nt) {
                    acc[mt][nt] = __builtin_amdgcn_mfma_f32_16x16x32_bf16(ah[mt], bh[nt], acc[mt][nt], 0, 0, 0);
                    acc[mt][nt] = __builtin_amdgcn_mfma_f32_16x16x32_bf16(ah[mt], bl[nt], acc[mt][nt], 0, 0, 0);
                    acc[mt][nt] = __builtin_amdgcn_mfma_f32_16x16x32_bf16(al[mt], bh[nt], acc[mt][nt], 0, 0, 0);
                }
            }
        }
        __syncthreads();
    }

    // ---- epilogue: per-wave top-2 over its 32 experts, per token.
    // C/D layout (16x16): col = lane&15 (expert), row = quad*4 + reg (token).
    #pragma unroll
    for (int mt = 0; mt < 4; ++mt) {
        #pragma unroll
        for (int r = 0; r < 4; ++r) {
            float s0 = acc[mt][0][r]; int e0 = wv * 32 + col;
            float s1 = acc[mt][1][r]; int e1 = e0 + 16;
            float t1s, t2s; int t1e, t2e;
            if (s1 > s0) { t1s = s1; t1e = e1; t2s = s0; t2e = e0; }
            else         { t1s = s0; t1e = e0; t2s = s1; t2e = e1; }
            #pragma unroll
            for (int m = 1; m <= 8; m <<= 1) {
                float o1s = __shfl_xor(t1s, m); int o1e = __shfl_xor(t1e, m);
                float o2s = __shfl_xor(t2s, m); int o2e = __shfl_xor(t2e, m);
                bool o1_top = (o1s > t1s) || (o1s == t1s && o1e < t1e);
                if (o1_top) {
                    bool keep_t1 = (t1s > o2s) || (t1s == o2s && t1e < o2e);
                    t2s = keep_t1 ? t1s : o2s; t2e = keep_t1 ? t1e : o2e;
                    t1s = o1s; t1e = o1e;
                } else {
                    bool o1_2nd = (o1s > t2s) || (o1s == t2s && o1e < t2e);
                    if (o1_2nd) { t2s = o1s; t2e = o1e; }
                }
            }
            if (col == 0) {
                int tok = mt * 16 + quad * 4 + r;
                cand[wv][tok] = make_float4(t1s, __int_as_float(t1e), t2s, __int_as_float(t2e));
            }
        }
    }
    __syncthreads();

    // ---- final merge across waves; write outputs + near-tie flags
    if (tid < MB) {
        float4 c0 = cand[0][tid];
        float t1s = c0.x; int t1e = __float_as_int(c0.y);
        float t2s = c0.z; int t2e = __float_as_int(c0.w);
        #pragma unroll
        for (int wvi = 1; wvi < NWAVES; ++wvi) {
            float4 c = cand[wvi][tid];
            float o1s = c.x; int o1e = __float_as_int(c.y);
            float o2s = c.z; int o2e = __float_as_int(c.w);
            bool o1_top = (o1s > t1s) || (o1s == t1s && o1e < t1e);
            if (o1_top) {
                bool keep_t1 = (t1s > o2s) || (t1s == o2s && t1e < o2e);
                t2s = keep_t1 ? t1s : o2s; t2e = keep_t1 ? t1e : o2e;
                t1s = o1s; t1e = o1e;
            } else {
                bool o1_2nd = (o1s > t2s) || (o1s == t2s && o1e < t2e);
                if (o1_2nd) { t2s = o1s; t2e = o1e; }
            }
        }
        const int gtok = tok0 + tid;
        out[gtok] = 1.0f;                       // STE forward value at argmax
        out[NUM_TOKENS + gtok] = (float)t1e;    // index as float
        if (t1s - t2s < MARGIN) {
            int slot = atomicAdd(counter, 1);
            if (slot < CAP) entries[slot] = make_int4(gtok, t1e, t2e, 0);
        }
    }
}

// ---------------------------------------------------------------- kernel 3
// fp64 re-verification of near-tie tokens (one wave per flagged token).
__global__ void refine(const float* __restrict__ x,
                       const float* __restrict__ w,
                       const int* __restrict__ counter,
                       const int4* __restrict__ entries,
                       float* __restrict__ out) {
    const int gwave  = (blockIdx.x * blockDim.x + threadIdx.x) >> 6;
    const int lane   = threadIdx.x & 63;
    const int nwaves = (gridDim.x * blockDim.x) >> 6;
    int n = *counter; if (n > CAP) n = CAP;
    for (int i = gwave; i < n; i += nwaves) {
        int4 e = entries[i];
        const float* xr = x + (size_t)e.x * DIM;
        const float* w1 = w + (size_t)e.y * DIM;
        const float* w2 = w + (size_t)e.z * DIM;
        double d1 = 0.0, d2 = 0.0;
        for (int k = lane; k < DIM; k += 64) {
            double xv = (double)xr[k];
            d1 += xv * (double)w1[k];
            d2 += xv * (double)w2[k];
        }
        #pragma unroll
        for (int m = 32; m > 0; m >>= 1) {
            d1 += __shfl_xor(d1, m);
            d2 += __shfl_xor(d2, m);
        }
        if (lane == 0) {
            int best = (d1 > d2) ? e.y : ((d2 > d1) ? e.z : (e.y < e.z ? e.y : e.z));
            out[NUM_TOKENS + e.x] = (float)best;
        }
    }
}

// ---------------------------------------------------------------- launcher
extern "C" void kernel_launch(void* const* d_in, const int* in_sizes, int n_in,
                              void* d_out, int out_size, void* d_ws, size_t ws_size,
                              hipStream_t stream) {
    const float* x = (const float*)d_in[0];
    const float* w = (const float*)d_in[1];
    float* out = (float*)d_out;

    char* ws = (char*)d_ws;
    unsigned short* whi = (unsigned short*)ws;                                // 2 MB
    unsigned short* wlo = (unsigned short*)(ws + (size_t)NEXP * DIM * 2);     // 2 MB
    int*  counter = (int*)(ws + (size_t)NEXP * DIM * 4);
    int4* entries = (int4*)(ws + (size_t)NEXP * DIM * 4 + 16);                // 256 KB

    split_weights<<<256, 256, 0, stream>>>(w, whi, wlo, counter);
    gate_main<<<NUM_TOKENS / MB, 512, 0, stream>>>(x, whi, wlo, out, counter, entries);
    refine<<<32, 256, 0, stream>>>(x, w, counter, entries, out);
}

// Round 3
// 440.446 us; speedup vs baseline: 1.2200x; 1.1303x over previous
//
#include <hip/hip_runtime.h>
#include <stdint.h>

#define NUM_TOKENS 16384
#define DIM        4096
#define NEXP       256
#define MB         64      // tokens per block
#define BK         64      // K per staging step
#define APAD       72      // A row stride (+8 kills bank conflicts, keeps 16B align)
#define NWAVES     8
#define MARGIN     0.025f  // ~8.6 sigma of the pure-bf16 gap error (std ~2.9e-3)
#define CAP        16384   // refinement list capacity

typedef __attribute__((ext_vector_type(4))) float   f32x4;
typedef __attribute__((ext_vector_type(8))) __bf16  bf16x8;
typedef __attribute__((ext_vector_type(8))) unsigned short u16x8;

static __device__ __forceinline__ unsigned short f32_to_bf16(float f) {
    unsigned int u = __float_as_uint(f);
    u += 0x7fffu + ((u >> 16) & 1u);     // round-to-nearest-even
    return (unsigned short)(u >> 16);
}

// ---------------------------------------------------------------- kernel 1
// Convert weight fp32 -> bf16 (hi only); zero the refinement counter.
__global__ void cvt_weights(const float* __restrict__ w,
                            unsigned short* __restrict__ wh,
                            int* __restrict__ counter) {
    if (blockIdx.x == 0 && threadIdx.x == 0) *counter = 0;
    const int n4 = NEXP * DIM / 4;
    const int stride = gridDim.x * blockDim.x;
    for (int i = blockIdx.x * blockDim.x + threadIdx.x; i < n4; i += stride) {
        float4 v = ((const float4*)w)[i];
        ushort4 h;
        h.x = f32_to_bf16(v.x); h.y = f32_to_bf16(v.y);
        h.z = f32_to_bf16(v.z); h.w = f32_to_bf16(v.w);
        ((ushort4*)wh)[i] = h;
    }
}

// ---------------------------------------------------------------- kernel 2
// Pure-bf16 GEMM (64 tokens x 256 experts per block) + fused top-2.
// Double-buffered LDS: next tile's B-DMA + x register prefetch are issued
// BEFORE computing the current tile, hiding HBM/L2 latency at 1 block/CU.
// B LDS uses an XOR chunk swizzle realized on the DMA source address.
__global__ __launch_bounds__(512, 2) void gate_main(
    const float* __restrict__ x,
    const unsigned short* __restrict__ wh,
    float* __restrict__ out,           // [0,T) weights, [T,2T) indices (as float)
    int* __restrict__ counter,
    int4* __restrict__ entries)
{
    __shared__ unsigned short lAh[2][MB][APAD];    // 18 KB
    __shared__ unsigned short lBh[2][NEXP * BK];   // 64 KB
    __shared__ float4 cand[NWAVES][MB];            // 8 KB

    const int tid  = threadIdx.x;
    const int wv   = tid >> 6;          // wave 0..7 -> experts [wv*32, wv*32+32)
    const int lane = tid & 63;
    const int tok0 = blockIdx.x * MB;

    // A staging: thread covers token ta, k-segment kseg..kseg+8
    const int ta   = tid >> 3;          // 0..63
    const int kseg = (tid & 7) * 8;     // 0..56
    const float* xrow = x + (size_t)(tok0 + ta) * DIM + kseg;

    // B staging coords (XOR-swizzled source chunk): lane l writes LDS chunk
    // (l&7) of expert base+(l>>3); slot holds global chunk ((l&7) ^ (e&7)).
    const int esub   = lane >> 3;                 // == e&7
    const int bk_off = ((lane & 7) ^ esub) * 8;   // swizzled source element offset

    const int quad = lane >> 4;
    const int col  = lane & 15;

    f32x4 acc[4][2];
    #pragma unroll
    for (int mt = 0; mt < 4; ++mt) {
        acc[mt][0] = f32x4{0.f, 0.f, 0.f, 0.f};
        acc[mt][1] = f32x4{0.f, 0.f, 0.f, 0.f};
    }

    // ---- prologue: stage tile 0 into buffer 0
    {
        #pragma unroll
        for (int jj = 0; jj < 4; ++jj) {
            const int e = jj * 64 + wv * 8 + esub;
            const unsigned short* gh = wh + (size_t)e * DIM + bk_off;
            unsigned short* dh = &lBh[0][jj * 4096 + wv * 512]; // wave-uniform base
            __builtin_amdgcn_global_load_lds(
                (const __attribute__((address_space(1))) unsigned int*)gh,
                (__attribute__((address_space(3))) unsigned int*)dh, 16, 0, 0);
        }
        float4 v0 = *(const float4*)(xrow);
        float4 v1 = *(const float4*)(xrow + 4);
        u16x8 vh;
        vh[0] = f32_to_bf16(v0.x); vh[1] = f32_to_bf16(v0.y);
        vh[2] = f32_to_bf16(v0.z); vh[3] = f32_to_bf16(v0.w);
        vh[4] = f32_to_bf16(v1.x); vh[5] = f32_to_bf16(v1.y);
        vh[6] = f32_to_bf16(v1.z); vh[7] = f32_to_bf16(v1.w);
        *(u16x8*)&lAh[0][ta][kseg] = vh;
        __syncthreads();
    }

    int cur = 0;
    for (int k0 = 0; k0 < DIM; k0 += BK) {
        const int nxt = cur ^ 1;
        const bool has_next = (k0 + BK) < DIM;   // uniform
        float4 v0, v1;

        // ---- issue next tile's loads FIRST (hide latency under compute)
        if (has_next) {
            #pragma unroll
            for (int jj = 0; jj < 4; ++jj) {
                const int e = jj * 64 + wv * 8 + esub;
                const unsigned short* gh = wh + (size_t)e * DIM + (k0 + BK) + bk_off;
                unsigned short* dh = &lBh[nxt][jj * 4096 + wv * 512];
                __builtin_amdgcn_global_load_lds(
                    (const __attribute__((address_space(1))) unsigned int*)gh,
                    (__attribute__((address_space(3))) unsigned int*)dh, 16, 0, 0);
            }
            v0 = *(const float4*)(xrow + k0 + BK);
            v1 = *(const float4*)(xrow + k0 + BK + 4);
        }

        // ---- compute current tile: 2 k-subtiles of 32, 8 MFMAs each
        #pragma unroll
        for (int kk = 0; kk < BK; kk += 32) {
            const int kc = kk >> 3;               // chunk base: 0 or 4
            bf16x8 ah[4], bh[2];
            #pragma unroll
            for (int mt = 0; mt < 4; ++mt)
                ah[mt] = *(const bf16x8*)&lAh[cur][mt * 16 + col][kk + quad * 8];
            #pragma unroll
            for (int nt = 0; nt < 2; ++nt) {
                const int e = wv * 32 + nt * 16 + col;
                const int cpos = (((kc + quad) ^ (e & 7)) * 8); // unswizzle
                bh[nt] = *(const bf16x8*)&lBh[cur][e * BK + cpos];
            }
            #pragma unroll
            for (int mt = 0; mt < 4; ++mt)
                #pragma unroll
                for (int nt = 0; nt < 2; ++nt)
                    acc[mt][nt] = __builtin_amdgcn_mfma_f32_16x16x32_bf16(
                        ah[mt], bh[nt], acc[mt][nt], 0, 0, 0);
        }

        // ---- convert + store next A tile (x regs have arrived by now)
        if (has_next) {
            u16x8 vh;
            vh[0] = f32_to_bf16(v0.x); vh[1] = f32_to_bf16(v0.y);
            vh[2] = f32_to_bf16(v0.z); vh[3] = f32_to_bf16(v0.w);
            vh[4] = f32_to_bf16(v1.x); vh[5] = f32_to_bf16(v1.y);
            vh[6] = f32_to_bf16(v1.z); vh[7] = f32_to_bf16(v1.w);
            *(u16x8*)&lAh[nxt][ta][kseg] = vh;
        }
        __syncthreads();
        cur = nxt;
    }

    // ---- epilogue: per-wave top-2 over its 32 experts, per token.
    // C/D layout (16x16): col = lane&15 (expert), row = quad*4 + reg (token).
    #pragma unroll
    for (int mt = 0; mt < 4; ++mt) {
        #pragma unroll
        for (int r = 0; r < 4; ++r) {
            float s0 = acc[mt][0][r]; int e0 = wv * 32 + col;
            float s1 = acc[mt][1][r]; int e1 = e0 + 16;
            float t1s, t2s; int t1e, t2e;
            if (s1 > s0) { t1s = s1; t1e = e1; t2s = s0; t2e = e0; }
            else         { t1s = s0; t1e = e0; t2s = s1; t2e = e1; }
            #pragma unroll
            for (int m = 1; m <= 8; m <<= 1) {
                float o1s = __shfl_xor(t1s, m); int o1e = __shfl_xor(t1e, m);
                float o2s = __shfl_xor(t2s, m); int o2e = __shfl_xor(t2e, m);
                bool o1_top = (o1s > t1s) || (o1s == t1s && o1e < t1e);
                if (o1_top) {
                    bool keep_t1 = (t1s > o2s) || (t1s == o2s && t1e < o2e);
                    t2s = keep_t1 ? t1s : o2s; t2e = keep_t1 ? t1e : o2e;
                    t1s = o1s; t1e = o1e;
                } else {
                    bool o1_2nd = (o1s > t2s) || (o1s == t2s && o1e < t2e);
                    if (o1_2nd) { t2s = o1s; t2e = o1e; }
                }
            }
            if (col == 0) {
                int tok = mt * 16 + quad * 4 + r;
                cand[wv][tok] = make_float4(t1s, __int_as_float(t1e), t2s, __int_as_float(t2e));
            }
        }
    }
    __syncthreads();

    // ---- final merge across waves; write outputs + near-tie flags
    if (tid < MB) {
        float4 c0 = cand[0][tid];
        float t1s = c0.x; int t1e = __float_as_int(c0.y);
        float t2s = c0.z; int t2e = __float_as_int(c0.w);
        #pragma unroll
        for (int wvi = 1; wvi < NWAVES; ++wvi) {
            float4 c = cand[wvi][tid];
            float o1s = c.x; int o1e = __float_as_int(c.y);
            float o2s = c.z; int o2e = __float_as_int(c.w);
            bool o1_top = (o1s > t1s) || (o1s == t1s && o1e < t1e);
            if (o1_top) {
                bool keep_t1 = (t1s > o2s) || (t1s == o2s && t1e < o2e);
                t2s = keep_t1 ? t1s : o2s; t2e = keep_t1 ? t1e : o2e;
                t1s = o1s; t1e = o1e;
            } else {
                bool o1_2nd = (o1s > t2s) || (o1s == t2s && o1e < t2e);
                if (o1_2nd) { t2s = o1s; t2e = o1e; }
            }
        }
        const int gtok = tok0 + tid;
        out[gtok] = 1.0f;                       // STE forward value at argmax
        out[NUM_TOKENS + gtok] = (float)t1e;    // index as float
        if (t1s - t2s < MARGIN) {
            int slot = atomicAdd(counter, 1);
            if (slot < CAP) entries[slot] = make_int4(gtok, t1e, t2e, 0);
        }
    }
}

// ---------------------------------------------------------------- kernel 3
// fp64 re-verification of near-tie tokens (one wave per flagged token).
__global__ void refine(const float* __restrict__ x,
                       const float* __restrict__ w,
                       const int* __restrict__ counter,
                       const int4* __restrict__ entries,
                       float* __restrict__ out) {
    const int gwave  = (blockIdx.x * blockDim.x + threadIdx.x) >> 6;
    const int lane   = threadIdx.x & 63;
    const int nwaves = (gridDim.x * blockDim.x) >> 6;
    int n = *counter; if (n > CAP) n = CAP;
    for (int i = gwave; i < n; i += nwaves) {
        int4 e = entries[i];
        const float* xr = x + (size_t)e.x * DIM;
        const float* w1 = w + (size_t)e.y * DIM;
        const float* w2 = w + (size_t)e.z * DIM;
        double d1 = 0.0, d2 = 0.0;
        for (int k = lane; k < DIM; k += 64) {
            double xv = (double)xr[k];
            d1 += xv * (double)w1[k];
            d2 += xv * (double)w2[k];
        }
        #pragma unroll
        for (int m = 32; m > 0; m >>= 1) {
            d1 += __shfl_xor(d1, m);
            d2 += __shfl_xor(d2, m);
        }
        if (lane == 0) {
            int best = (d1 > d2) ? e.y : ((d2 > d1) ? e.z : (e.y < e.z ? e.y : e.z));
            out[NUM_TOKENS + e.x] = (float)best;
        }
    }
}

// ---------------------------------------------------------------- launcher
extern "C" void kernel_launch(void* const* d_in, const int* in_sizes, int n_in,
                              void* d_out, int out_size, void* d_ws, size_t ws_size,
                              hipStream_t stream) {
    const float* x = (const float*)d_in[0];
    const float* w = (const float*)d_in[1];
    float* out = (float*)d_out;

    char* ws = (char*)d_ws;
    unsigned short* wh = (unsigned short*)ws;                                 // 2 MB
    int*  counter = (int*)(ws + (size_t)NEXP * DIM * 2);
    int4* entries = (int4*)(ws + (size_t)NEXP * DIM * 2 + 16);                // 256 KB

    cvt_weights<<<256, 256, 0, stream>>>(w, wh, counter);
    gate_main<<<NUM_TOKENS / MB, 512, 0, stream>>>(x, wh, out, counter, entries);
    refine<<<256, 256, 0, stream>>>(x, w, counter, entries, out);
}

// Round 4
// 435.393 us; speedup vs baseline: 1.2342x; 1.0116x over previous
//
#include <hip/hip_runtime.h>
#include <stdint.h>

#define NUM_TOKENS 16384
#define DIM        4096
#define NEXP       256
#define MB         64      // tokens per tile
#define BK         64      // K per staging step
#define KHALF      2048    // K handled per block (DIM/2)
#define NITER      (KHALF / BK)
#define APAD       72      // A row stride (+8 kills bank conflicts, keeps 16B align)
#define MARGIN     0.025f  // ~8.6 sigma of the pure-bf16 gap error (std ~2.9e-3)
#define CAP        16384   // refinement list capacity

typedef __attribute__((ext_vector_type(4))) float   f32x4;
typedef __attribute__((ext_vector_type(8))) __bf16  bf16x8;
typedef __attribute__((ext_vector_type(8))) unsigned short u16x8;

static __device__ __forceinline__ unsigned short f32_to_bf16(float f) {
    unsigned int u = __float_as_uint(f);
    u += 0x7fffu + ((u >> 16) & 1u);     // round-to-nearest-even
    return (unsigned short)(u >> 16);
}

// ---------------------------------------------------------------- kernel 1
// Convert weight fp32 -> bf16; zero the refinement counter.
__global__ void cvt_weights(const float* __restrict__ w,
                            unsigned short* __restrict__ wh,
                            int* __restrict__ counter) {
    if (blockIdx.x == 0 && threadIdx.x == 0) *counter = 0;
    const int n4 = NEXP * DIM / 4;
    const int stride = gridDim.x * blockDim.x;
    for (int i = blockIdx.x * blockDim.x + threadIdx.x; i < n4; i += stride) {
        float4 v = ((const float4*)w)[i];
        ushort4 h;
        h.x = f32_to_bf16(v.x); h.y = f32_to_bf16(v.y);
        h.z = f32_to_bf16(v.z); h.w = f32_to_bf16(v.w);
        ((ushort4*)wh)[i] = h;
    }
}

// ---------------------------------------------------------------- kernel 2
// bf16 GEMM partial: block = (token tile, K-half). 256 thr / 4 waves; each
// wave: 64 tokens x 64 experts (mt=4, nt=4). Single-buffered LDS; grid=512
// gives 2 blocks/CU so inter-block overlap hides the barrier vmcnt drain.
// B LDS uses an XOR chunk swizzle realized on the DMA source address.
__global__ __launch_bounds__(256, 3) void gate_main(
    const float* __restrict__ x,
    const unsigned short* __restrict__ wh,
    float* __restrict__ ps)            // [2][NUM_TOKENS][NEXP] partial scores
{
    __shared__ unsigned short lAh[MB][APAD];    // 9 KB
    __shared__ unsigned short lBh[NEXP * BK];   // 32 KB

    const int tid  = threadIdx.x;
    const int wv   = tid >> 6;          // wave 0..3 -> experts [wv*64, wv*64+64)
    const int lane = tid & 63;
    const int tile = blockIdx.x >> 1;
    const int half = blockIdx.x & 1;
    const int tok0 = tile * MB;
    const int kbase = half * KHALF;

    // A staging: thread covers token ta, 16 floats at kseg
    const int ta   = tid >> 2;          // 0..63
    const int kseg = (tid & 3) * 16;    // 0..48
    const float* xrow = x + (size_t)(tok0 + ta) * DIM + kbase + kseg;

    // B staging coords (XOR-swizzled source chunk): lane l writes LDS chunk
    // (l&7) of expert base+(l>>3); slot holds global chunk ((l&7) ^ (e&7)).
    const int esub   = lane >> 3;                 // == e&7
    const int bk_off = ((lane & 7) ^ esub) * 8;   // swizzled source element offset

    const int quad = lane >> 4;
    const int col  = lane & 15;

    f32x4 acc[4][4];
    #pragma unroll
    for (int mt = 0; mt < 4; ++mt)
        #pragma unroll
        for (int nt = 0; nt < 4; ++nt)
            acc[mt][nt] = f32x4{0.f, 0.f, 0.f, 0.f};

    float4 xv0 = *(const float4*)(xrow);
    float4 xv1 = *(const float4*)(xrow + 4);
    float4 xv2 = *(const float4*)(xrow + 8);
    float4 xv3 = *(const float4*)(xrow + 12);

    for (int it = 0; it < NITER; ++it) {
        const int k0 = it * BK;

        // ---- stage B via async DMA (8 instrs/wave cover this wave's 64 experts)
        #pragma unroll
        for (int jj = 0; jj < 8; ++jj) {
            const int e = wv * 64 + jj * 8 + esub;
            const unsigned short* gh = wh + (size_t)e * DIM + kbase + k0 + bk_off;
            unsigned short* dh = &lBh[(wv * 64 + jj * 8) * BK]; // wave-uniform base
            __builtin_amdgcn_global_load_lds(
                (const __attribute__((address_space(1))) unsigned int*)gh,
                (__attribute__((address_space(3))) unsigned int*)dh, 16, 0, 0);
        }

        // ---- convert + store A (16 bf16/thread)
        {
            u16x8 h0, h1;
            h0[0] = f32_to_bf16(xv0.x); h0[1] = f32_to_bf16(xv0.y);
            h0[2] = f32_to_bf16(xv0.z); h0[3] = f32_to_bf16(xv0.w);
            h0[4] = f32_to_bf16(xv1.x); h0[5] = f32_to_bf16(xv1.y);
            h0[6] = f32_to_bf16(xv1.z); h0[7] = f32_to_bf16(xv1.w);
            h1[0] = f32_to_bf16(xv2.x); h1[1] = f32_to_bf16(xv2.y);
            h1[2] = f32_to_bf16(xv2.z); h1[3] = f32_to_bf16(xv2.w);
            h1[4] = f32_to_bf16(xv3.x); h1[5] = f32_to_bf16(xv3.y);
            h1[6] = f32_to_bf16(xv3.z); h1[7] = f32_to_bf16(xv3.w);
            *(u16x8*)&lAh[ta][kseg]     = h0;
            *(u16x8*)&lAh[ta][kseg + 8] = h1;
        }
        __syncthreads();   // drains DMA + lds writes (compiler vmcnt/lgkm 0)

        // ---- prefetch next iteration's x during compute
        if (it + 1 < NITER) {
            xv0 = *(const float4*)(xrow + (it + 1) * BK);
            xv1 = *(const float4*)(xrow + (it + 1) * BK + 4);
            xv2 = *(const float4*)(xrow + (it + 1) * BK + 8);
            xv3 = *(const float4*)(xrow + (it + 1) * BK + 12);
        }

        // ---- compute: 2 k-subtiles of 32; 16 MFMAs each
        #pragma unroll
        for (int kk = 0; kk < BK; kk += 32) {
            const int kc = kk >> 3;               // chunk base: 0 or 4
            bf16x8 ah[4], bh[4];
            #pragma unroll
            for (int mt = 0; mt < 4; ++mt)
                ah[mt] = *(const bf16x8*)&lAh[mt * 16 + col][kk + quad * 8];
            #pragma unroll
            for (int nt = 0; nt < 4; ++nt) {
                const int e = wv * 64 + nt * 16 + col;
                const int cpos = (((kc + quad) ^ (col & 7)) * 8); // unswizzle (e&7==col&7)
                bh[nt] = *(const bf16x8*)&lBh[e * BK + cpos];
            }
            #pragma unroll
            for (int mt = 0; mt < 4; ++mt)
                #pragma unroll
                for (int nt = 0; nt < 4; ++nt)
                    acc[mt][nt] = __builtin_amdgcn_mfma_f32_16x16x32_bf16(
                        ah[mt], bh[nt], acc[mt][nt], 0, 0, 0);
        }
        __syncthreads();   // protect LDS reuse
    }

    // ---- epilogue: store raw partial scores (coalesced 64B segments)
    float* base = ps + ((size_t)half * NUM_TOKENS + tok0) * NEXP;
    #pragma unroll
    for (int mt = 0; mt < 4; ++mt)
        #pragma unroll
        for (int r = 0; r < 4; ++r) {
            const int tok = mt * 16 + quad * 4 + r;
            #pragma unroll
            for (int nt = 0; nt < 4; ++nt)
                base[(size_t)tok * NEXP + wv * 64 + nt * 16 + col] = acc[mt][nt][r];
        }
}

// ---------------------------------------------------------------- kernel 3
// Sum the two K-half partials, top-2 + argmax per token, margin flagging.
__global__ void reduce_top2(const float* __restrict__ ps,
                            float* __restrict__ out,
                            int* __restrict__ counter,
                            int4* __restrict__ entries) {
    const int gw   = (blockIdx.x * blockDim.x + threadIdx.x) >> 6;
    const int lane = threadIdx.x & 63;
    const int nw   = (gridDim.x * blockDim.x) >> 6;
    for (int t = gw; t < NUM_TOKENS; t += nw) {
        const float4 a = *(const float4*)(ps + (size_t)t * NEXP + lane * 4);
        const float4 b = *(const float4*)(ps + ((size_t)NUM_TOKENS + t) * NEXP + lane * 4);
        float s[4] = {a.x + b.x, a.y + b.y, a.z + b.z, a.w + b.w};
        float t1s = s[0]; int t1e = lane * 4;
        float t2s = s[1]; int t2e = lane * 4 + 1;
        if (t2s > t1s) { float ts = t1s; int te = t1e; t1s = t2s; t1e = t2e; t2s = ts; t2e = te; }
        #pragma unroll
        for (int j = 2; j < 4; ++j) {
            if (s[j] > t1s)      { t2s = t1s; t2e = t1e; t1s = s[j]; t1e = lane * 4 + j; }
            else if (s[j] > t2s) { t2s = s[j]; t2e = lane * 4 + j; }
        }
        #pragma unroll
        for (int m = 1; m <= 32; m <<= 1) {
            float o1s = __shfl_xor(t1s, m); int o1e = __shfl_xor(t1e, m);
            float o2s = __shfl_xor(t2s, m); int o2e = __shfl_xor(t2e, m);
            bool o1_top = (o1s > t1s) || (o1s == t1s && o1e < t1e);
            if (o1_top) {
                bool keep_t1 = (t1s > o2s) || (t1s == o2s && t1e < o2e);
                t2s = keep_t1 ? t1s : o2s; t2e = keep_t1 ? t1e : o2e;
                t1s = o1s; t1e = o1e;
            } else {
                bool o1_2nd = (o1s > t2s) || (o1s == t2s && o1e < t2e);
                if (o1_2nd) { t2s = o1s; t2e = o1e; }
            }
        }
        if (lane == 0) {
            out[t] = 1.0f;                    // STE forward value at argmax
            out[NUM_TOKENS + t] = (float)t1e; // index as float
            if (t1s - t2s < MARGIN) {
                int slot = atomicAdd(counter, 1);
                if (slot < CAP) entries[slot] = make_int4(t, t1e, t2e, 0);
            }
        }
    }
}

// ---------------------------------------------------------------- kernel 4
// fp64 re-verification of near-tie tokens (one wave per flagged token).
__global__ void refine(const float* __restrict__ x,
                       const float* __restrict__ w,
                       const int* __restrict__ counter,
                       const int4* __restrict__ entries,
                       float* __restrict__ out) {
    const int gwave  = (blockIdx.x * blockDim.x + threadIdx.x) >> 6;
    const int lane   = threadIdx.x & 63;
    const int nwaves = (gridDim.x * blockDim.x) >> 6;
    int n = *counter; if (n > CAP) n = CAP;
    for (int i = gwave; i < n; i += nwaves) {
        int4 e = entries[i];
        const float* xr = x + (size_t)e.x * DIM;
        const float* w1 = w + (size_t)e.y * DIM;
        const float* w2 = w + (size_t)e.z * DIM;
        double d1 = 0.0, d2 = 0.0;
        for (int k = lane; k < DIM; k += 64) {
            double xv = (double)xr[k];
            d1 += xv * (double)w1[k];
            d2 += xv * (double)w2[k];
        }
        #pragma unroll
        for (int m = 32; m > 0; m >>= 1) {
            d1 += __shfl_xor(d1, m);
            d2 += __shfl_xor(d2, m);
        }
        if (lane == 0) {
            int best = (d1 > d2) ? e.y : ((d2 > d1) ? e.z : (e.y < e.z ? e.y : e.z));
            out[NUM_TOKENS + e.x] = (float)best;
        }
    }
}

// ---------------------------------------------------------------- launcher
extern "C" void kernel_launch(void* const* d_in, const int* in_sizes, int n_in,
                              void* d_out, int out_size, void* d_ws, size_t ws_size,
                              hipStream_t stream) {
    const float* x = (const float*)d_in[0];
    const float* w = (const float*)d_in[1];
    float* out = (float*)d_out;

    char* ws = (char*)d_ws;
    unsigned short* wh = (unsigned short*)ws;                     // 2 MB
    int*  counter = (int*)(ws + (2u << 20));
    int4* entries = (int4*)(ws + (2u << 20) + 16);                // 256 KB
    float* ps     = (float*)(ws + (4u << 20));                    // 32 MB partials

    cvt_weights<<<256, 256, 0, stream>>>(w, wh, counter);
    gate_main<<<2 * NUM_TOKENS / MB, 256, 0, stream>>>(x, wh, ps);
    reduce_top2<<<512, 256, 0, stream>>>(ps, out, counter, entries);
    refine<<<256, 256, 0, stream>>>(x, w, counter, entries, out);
}